// Round 1
// baseline (778.406 us; speedup 1.0000x reference)
//
#include <hip/hip_runtime.h>

#define D 128

// Dual GEMM: support = x@W -> ws, outRoot = x@Wroot -> d_out.
// Combined N = 256 (blockIdx.y 0,1 -> support cols 0..127; 2,3 -> out cols 0..127)
// BM=64, BN=64, BK=16, 256 threads, TM=TN=4 register tile.
__global__ __launch_bounds__(256) void gemm_dual(
    const float* __restrict__ x, const float* __restrict__ W,
    const float* __restrict__ Wr, float* __restrict__ support,
    float* __restrict__ out, int M)
{
    __shared__ float As[16][64];
    __shared__ float Bs[16][64];
    const int tid = threadIdx.x;
    const int bx = blockIdx.x;      // row block
    const int by = blockIdx.y;      // col block 0..3
    const float* Wsrc = (by < 2) ? W : Wr;
    float* dst = (by < 2) ? support : out;
    const int cOff = (by & 1) * 64;

    const int tx = tid & 15, ty = tid >> 4;
    float acc[4][4] = {};

    const int rowBase = bx * 64;
    // A-tile load mapping: 64 rows x 16 k, each thread one float4 along k
    const int lm  = tid & 63;          // row within tile
    const int lk4 = (tid >> 6) * 4;    // k group (0,4,8,12)
    // B-tile load mapping: 16 k-rows x 64 cols, each thread one float4 along cols
    const int bk_row = tid >> 4;        // 0..15
    const int bk_col = (tid & 15) * 4;  // 0..60

    for (int t = 0; t < 8; ++t) {
        const int k0 = t * 16;
        // As: x[rowBase+lm][k0+lk4 .. +3] -> As[lk4+j][lm] (transposed)
        const int row = rowBase + lm;
        float4 av = make_float4(0.f, 0.f, 0.f, 0.f);
        if (row < M) av = *(const float4*)(x + (size_t)row * D + k0 + lk4);
        As[lk4 + 0][lm] = av.x;
        As[lk4 + 1][lm] = av.y;
        As[lk4 + 2][lm] = av.z;
        As[lk4 + 3][lm] = av.w;
        // Bs: Wsrc[k0+bk_row][cOff+bk_col .. +3]
        const float4 bv = *(const float4*)(Wsrc + (size_t)(k0 + bk_row) * D + cOff + bk_col);
        *(float4*)&Bs[bk_row][bk_col] = bv;
        __syncthreads();
        #pragma unroll
        for (int kk = 0; kk < 16; ++kk) {
            const float4 a = *(const float4*)&As[kk][ty * 4];
            const float4 b = *(const float4*)&Bs[kk][tx * 4];
            const float aa[4] = {a.x, a.y, a.z, a.w};
            const float bb[4] = {b.x, b.y, b.z, b.w};
            #pragma unroll
            for (int i = 0; i < 4; ++i)
                #pragma unroll
                for (int j = 0; j < 4; ++j)
                    acc[i][j] += aa[i] * bb[j];
        }
        __syncthreads();
    }
    #pragma unroll
    for (int i = 0; i < 4; ++i) {
        const int row = rowBase + ty * 4 + i;
        if (row < M) {
            const float4 v = make_float4(acc[i][0], acc[i][1], acc[i][2], acc[i][3]);
            *(float4*)(dst + (size_t)row * D + cOff + tx * 4) = v;
        }
    }
}

// One 64-lane wave per edge: gather support[col] (float2/lane, 512B coalesced),
// scale by val, atomicAdd into out[row].
__global__ __launch_bounds__(256) void edge_agg(
    const int* __restrict__ rows, const int* __restrict__ cols,
    const float* __restrict__ vals, const float* __restrict__ support,
    float* __restrict__ out, int E)
{
    const int gid = blockIdx.x * blockDim.x + threadIdx.x;
    const int e = gid >> 6;
    const int lane = threadIdx.x & 63;
    if (e >= E) return;
    const int r = rows[e];
    const int c = cols[e];
    const float v = vals[e];
    const float2 s = *(const float2*)(support + (size_t)c * D + lane * 2);
    float* o = out + (size_t)r * D + lane * 2;
    atomicAdd(o + 0, s.x * v);
    atomicAdd(o + 1, s.y * v);
}

extern "C" void kernel_launch(void* const* d_in, const int* in_sizes, int n_in,
                              void* d_out, int out_size, void* d_ws, size_t ws_size,
                              hipStream_t stream) {
    const float* x     = (const float*)d_in[0];
    const int*   erows = (const int*)d_in[1];
    const int*   ecols = (const int*)d_in[2];
    const float* evals = (const float*)d_in[3];
    const float* W     = (const float*)d_in[4];
    const float* Wr    = (const float*)d_in[5];
    float* out = (float*)d_out;
    float* support = (float*)d_ws;   // N*D*4 = 25.6 MB scratch

    const int M = in_sizes[0] / D;   // 50000
    const int E = in_sizes[1];       // 800000

    dim3 grid((M + 63) / 64, 4);
    gemm_dual<<<grid, 256, 0, stream>>>(x, W, Wr, support, out, M);

    const long long total_threads = (long long)E * 64;
    const int blocks = (int)((total_threads + 255) / 256);
    edge_agg<<<blocks, 256, 0, stream>>>(erows, ecols, evals, support, out, E);
}

// Round 2
// 391.934 us; speedup vs baseline: 1.9861x; 1.9861x over previous
//
#include <hip/hip_runtime.h>

#define D 128

// ---------------- Dual GEMM: support = x@W -> ws, out = x@Wroot -> d_out ----
__global__ __launch_bounds__(256) void gemm_dual(
    const float* __restrict__ x, const float* __restrict__ W,
    const float* __restrict__ Wr, float* __restrict__ support,
    float* __restrict__ out, int M)
{
    __shared__ float As[16][64];
    __shared__ float Bs[16][64];
    const int tid = threadIdx.x;
    const int bx = blockIdx.x;
    const int by = blockIdx.y;      // 0,1 -> support; 2,3 -> out
    const float* Wsrc = (by < 2) ? W : Wr;
    float* dst = (by < 2) ? support : out;
    const int cOff = (by & 1) * 64;

    const int tx = tid & 15, ty = tid >> 4;
    float acc[4][4] = {};

    const int rowBase = bx * 64;
    const int lm  = tid & 63;
    const int lk4 = (tid >> 6) * 4;
    const int bk_row = tid >> 4;
    const int bk_col = (tid & 15) * 4;

    for (int t = 0; t < 8; ++t) {
        const int k0 = t * 16;
        const int row = rowBase + lm;
        float4 av = make_float4(0.f, 0.f, 0.f, 0.f);
        if (row < M) av = *(const float4*)(x + (size_t)row * D + k0 + lk4);
        As[lk4 + 0][lm] = av.x;
        As[lk4 + 1][lm] = av.y;
        As[lk4 + 2][lm] = av.z;
        As[lk4 + 3][lm] = av.w;
        const float4 bv = *(const float4*)(Wsrc + (size_t)(k0 + bk_row) * D + cOff + bk_col);
        *(float4*)&Bs[bk_row][bk_col] = bv;
        __syncthreads();
        #pragma unroll
        for (int kk = 0; kk < 16; ++kk) {
            const float4 a = *(const float4*)&As[kk][ty * 4];
            const float4 b = *(const float4*)&Bs[kk][tx * 4];
            const float aa[4] = {a.x, a.y, a.z, a.w};
            const float bb[4] = {b.x, b.y, b.z, b.w};
            #pragma unroll
            for (int i = 0; i < 4; ++i)
                #pragma unroll
                for (int j = 0; j < 4; ++j)
                    acc[i][j] += aa[i] * bb[j];
        }
        __syncthreads();
    }
    #pragma unroll
    for (int i = 0; i < 4; ++i) {
        const int row = rowBase + ty * 4 + i;
        if (row < M) {
            const float4 v = make_float4(acc[i][0], acc[i][1], acc[i][2], acc[i][3]);
            *(float4*)(dst + (size_t)row * D + cOff + tx * 4) = v;
        }
    }
}

// ---------------- CSR build ------------------------------------------------
__global__ __launch_bounds__(256) void edge_histogram(
    const int* __restrict__ rows, int* __restrict__ counts, int E)
{
    const int e = blockIdx.x * 256 + threadIdx.x;
    if (e < E) atomicAdd(&counts[rows[e]], 1);
}

// Single-block two-level exclusive scan of counts[0..n) -> row_start[0..n],
// also duplicated into cursor[0..n).
__global__ __launch_bounds__(1024) void scan_counts(
    const int* __restrict__ counts, int* __restrict__ row_start,
    int* __restrict__ cursor, int n)
{
    __shared__ int tmp[1024];
    const int t = threadIdx.x;
    const int CH = (n + 1023) / 1024;
    const int lo = t * CH;
    const int hi = min(lo + CH, n);
    int sum = 0;
    for (int i = lo; i < hi; ++i) sum += counts[i];
    tmp[t] = sum;
    __syncthreads();
    // Hillis-Steele inclusive scan over 1024 partials
    for (int off = 1; off < 1024; off <<= 1) {
        int v = (t >= off) ? tmp[t - off] : 0;
        __syncthreads();
        tmp[t] += v;
        __syncthreads();
    }
    int running = tmp[t] - sum;   // exclusive prefix for this chunk
    for (int i = lo; i < hi; ++i) {
        row_start[i] = running;
        cursor[i] = running;
        running += counts[i];
    }
    if (t == 1023) row_start[n] = tmp[1023];
}

__global__ __launch_bounds__(256) void edge_scatter(
    const int* __restrict__ rows, const int* __restrict__ cols,
    const float* __restrict__ vals, int* __restrict__ cursor,
    int2* __restrict__ sorted, int E)
{
    const int e = blockIdx.x * 256 + threadIdx.x;
    if (e >= E) return;
    const int r = rows[e];
    const int pos = atomicAdd(&cursor[r], 1);
    sorted[pos] = make_int2(cols[e], __float_as_int(vals[e]));
}

// ---------------- Aggregation: one wave per row, no atomics ----------------
__global__ __launch_bounds__(256) void row_aggregate(
    const int* __restrict__ row_start, const int2* __restrict__ sorted,
    const float* __restrict__ support, float* __restrict__ out, int N)
{
    const int row = blockIdx.x * 4 + (threadIdx.x >> 6);
    const int lane = threadIdx.x & 63;
    if (row >= N) return;
    const int s = row_start[row];
    const int e = row_start[row + 1];
    if (s == e) return;   // out already holds x@Wr for this row

    float2 acc0 = make_float2(0.f, 0.f);
    float2 acc1 = make_float2(0.f, 0.f);
    int i = s;
    for (; i + 1 < e; i += 2) {
        const int2 e0 = sorted[i];
        const int2 e1 = sorted[i + 1];
        const float2 s0 = *(const float2*)(support + (size_t)e0.x * D + lane * 2);
        const float2 s1 = *(const float2*)(support + (size_t)e1.x * D + lane * 2);
        const float v0 = __int_as_float(e0.y);
        const float v1 = __int_as_float(e1.y);
        acc0.x += s0.x * v0; acc0.y += s0.y * v0;
        acc1.x += s1.x * v1; acc1.y += s1.y * v1;
    }
    if (i < e) {
        const int2 e0 = sorted[i];
        const float2 s0 = *(const float2*)(support + (size_t)e0.x * D + lane * 2);
        const float v0 = __int_as_float(e0.y);
        acc0.x += s0.x * v0; acc0.y += s0.y * v0;
    }
    float* o = out + (size_t)row * D + lane * 2;
    float2 ov = *(const float2*)o;
    ov.x += acc0.x + acc1.x;
    ov.y += acc0.y + acc1.y;
    *(float2*)o = ov;
}

extern "C" void kernel_launch(void* const* d_in, const int* in_sizes, int n_in,
                              void* d_out, int out_size, void* d_ws, size_t ws_size,
                              hipStream_t stream) {
    const float* x     = (const float*)d_in[0];
    const int*   erows = (const int*)d_in[1];
    const int*   ecols = (const int*)d_in[2];
    const float* evals = (const float*)d_in[3];
    const float* W     = (const float*)d_in[4];
    const float* Wr    = (const float*)d_in[5];
    float* out = (float*)d_out;

    const int M = in_sizes[0] / D;   // N = 50000
    const int E = in_sizes[1];       // 800000

    // ws layout
    float* support  = (float*)d_ws;                       // M*D floats
    int*   counts   = (int*)(support + (size_t)M * D);    // M
    int*   row_start= counts + M;                         // M+2 (pad for 8B align)
    int*   cursor   = row_start + M + 2;                  // M
    int2*  sorted   = (int2*)(cursor + M);                // E int2

    // 1. GEMMs
    dim3 grid((M + 63) / 64, 4);
    gemm_dual<<<grid, 256, 0, stream>>>(x, W, Wr, support, out, M);

    // 2. CSR build
    hipMemsetAsync(counts, 0, (size_t)M * sizeof(int), stream);
    const int eb = (E + 255) / 256;
    edge_histogram<<<eb, 256, 0, stream>>>(erows, counts, E);
    scan_counts<<<1, 1024, 0, stream>>>(counts, row_start, cursor, M);
    edge_scatter<<<eb, 256, 0, stream>>>(erows, ecols, evals, cursor, sorted, E);

    // 3. Aggregate (wave per row)
    row_aggregate<<<(M + 3) / 4, 256, 0, stream>>>(row_start, sorted, support, out, M);
}

// Round 3
// 285.080 us; speedup vs baseline: 2.7305x; 1.3748x over previous
//
#include <hip/hip_runtime.h>

#define D 128

// ---------------- Dual GEMM: support = x@W -> ws, out = x@Wroot -> d_out ----
__global__ __launch_bounds__(256) void gemm_dual(
    const float* __restrict__ x, const float* __restrict__ W,
    const float* __restrict__ Wr, float* __restrict__ support,
    float* __restrict__ out, int M)
{
    __shared__ float As[16][64];
    __shared__ float Bs[16][64];
    const int tid = threadIdx.x;
    const int bx = blockIdx.x;
    const int by = blockIdx.y;      // 0,1 -> support; 2,3 -> out
    const float* Wsrc = (by < 2) ? W : Wr;
    float* dst = (by < 2) ? support : out;
    const int cOff = (by & 1) * 64;

    const int tx = tid & 15, ty = tid >> 4;
    float acc[4][4] = {};

    const int rowBase = bx * 64;
    const int lm  = tid & 63;
    const int lk4 = (tid >> 6) * 4;
    const int bk_row = tid >> 4;
    const int bk_col = (tid & 15) * 4;

    for (int t = 0; t < 8; ++t) {
        const int k0 = t * 16;
        const int row = rowBase + lm;
        float4 av = make_float4(0.f, 0.f, 0.f, 0.f);
        if (row < M) av = *(const float4*)(x + (size_t)row * D + k0 + lk4);
        As[lk4 + 0][lm] = av.x;
        As[lk4 + 1][lm] = av.y;
        As[lk4 + 2][lm] = av.z;
        As[lk4 + 3][lm] = av.w;
        const float4 bv = *(const float4*)(Wsrc + (size_t)(k0 + bk_row) * D + cOff + bk_col);
        *(float4*)&Bs[bk_row][bk_col] = bv;
        __syncthreads();
        #pragma unroll
        for (int kk = 0; kk < 16; ++kk) {
            const float4 a = *(const float4*)&As[kk][ty * 4];
            const float4 b = *(const float4*)&Bs[kk][tx * 4];
            const float aa[4] = {a.x, a.y, a.z, a.w};
            const float bb[4] = {b.x, b.y, b.z, b.w};
            #pragma unroll
            for (int i = 0; i < 4; ++i)
                #pragma unroll
                for (int j = 0; j < 4; ++j)
                    acc[i][j] += aa[i] * bb[j];
        }
        __syncthreads();
    }
    #pragma unroll
    for (int i = 0; i < 4; ++i) {
        const int row = rowBase + ty * 4 + i;
        if (row < M) {
            const float4 v = make_float4(acc[i][0], acc[i][1], acc[i][2], acc[i][3]);
            *(float4*)(dst + (size_t)row * D + cOff + tx * 4) = v;
        }
    }
}

// ---------------- CSR build ------------------------------------------------
__global__ __launch_bounds__(256) void edge_histogram(
    const int* __restrict__ rows, int* __restrict__ counts, int E)
{
    const int e = blockIdx.x * 256 + threadIdx.x;
    if (e < E) atomicAdd(&counts[rows[e]], 1);
}

// Phase 1: per-block (1024 counts) local exclusive scan -> row_start (local),
// block total -> block_sums[b].
__global__ __launch_bounds__(256) void scan_local(
    const int* __restrict__ counts, int* __restrict__ row_start,
    int* __restrict__ block_sums, int n)
{
    __shared__ int tmp[256];
    const int b = blockIdx.x, t = threadIdx.x;
    const int base = b * 1024 + t * 4;
    int v0 = 0, v1 = 0, v2 = 0, v3 = 0;
    if (base + 3 < n) {
        const int4 q = *(const int4*)(counts + base);
        v0 = q.x; v1 = q.y; v2 = q.z; v3 = q.w;
    } else {
        if (base + 0 < n) v0 = counts[base + 0];
        if (base + 1 < n) v1 = counts[base + 1];
        if (base + 2 < n) v2 = counts[base + 2];
    }
    const int s01 = v0 + v1;
    const int tsum = s01 + v2 + v3;
    tmp[t] = tsum;
    __syncthreads();
    for (int off = 1; off < 256; off <<= 1) {
        const int u = (t >= off) ? tmp[t - off] : 0;
        __syncthreads();
        tmp[t] += u;
        __syncthreads();
    }
    const int excl = tmp[t] - tsum;
    const int e0 = excl;
    const int e1 = excl + v0;
    const int e2 = excl + s01;
    const int e3 = e2 + v2;
    if (base + 3 < n) {
        *(int4*)(row_start + base) = make_int4(e0, e1, e2, e3);
    } else {
        if (base + 0 < n) row_start[base + 0] = e0;
        if (base + 1 < n) row_start[base + 1] = e1;
        if (base + 2 < n) row_start[base + 2] = e2;
    }
    if (t == 255) block_sums[b] = tmp[255];
}

// Phase 2: exclusive scan of <=64 block sums (single wave-sized block).
__global__ __launch_bounds__(64) void scan_blocks(
    int* __restrict__ block_sums, int* __restrict__ row_start, int nb, int n)
{
    __shared__ int tmp[64];
    const int t = threadIdx.x;
    const int v = (t < nb) ? block_sums[t] : 0;
    tmp[t] = v;
    __syncthreads();
    for (int off = 1; off < 64; off <<= 1) {
        const int u = (t >= off) ? tmp[t - off] : 0;
        __syncthreads();
        tmp[t] += u;
        __syncthreads();
    }
    if (t < nb) block_sums[t] = tmp[t] - v;   // exclusive
    if (t == 63) row_start[n] = tmp[63];      // == E
}

// Phase 3: add block offsets in place; mirror into cursor.
__global__ __launch_bounds__(256) void add_offsets(
    const int* __restrict__ block_sums, int* __restrict__ row_start,
    int* __restrict__ cursor, int n)
{
    const int b = blockIdx.x;
    const int off = block_sums[b];
    const int base = b * 1024 + threadIdx.x * 4;
    if (base + 3 < n) {
        int4 q = *(const int4*)(row_start + base);
        q.x += off; q.y += off; q.z += off; q.w += off;
        *(int4*)(row_start + base) = q;
        *(int4*)(cursor + base) = q;
    } else {
        #pragma unroll
        for (int j = 0; j < 4; ++j) {
            const int i = base + j;
            if (i < n) {
                const int v = row_start[i] + off;
                row_start[i] = v;
                cursor[i] = v;
            }
        }
    }
}

__global__ __launch_bounds__(256) void edge_scatter(
    const int* __restrict__ rows, const int* __restrict__ cols,
    const float* __restrict__ vals, int* __restrict__ cursor,
    int2* __restrict__ sorted, int E)
{
    const int e = blockIdx.x * 256 + threadIdx.x;
    if (e >= E) return;
    const int r = rows[e];
    const int pos = atomicAdd(&cursor[r], 1);
    sorted[pos] = make_int2(cols[e], __float_as_int(vals[e]));
}

// ---------------- Aggregation: one wave per row, no atomics ----------------
__global__ __launch_bounds__(256) void row_aggregate(
    const int* __restrict__ row_start, const int2* __restrict__ sorted,
    const float* __restrict__ support, float* __restrict__ out, int N)
{
    const int row = blockIdx.x * 4 + (threadIdx.x >> 6);
    const int lane = threadIdx.x & 63;
    if (row >= N) return;
    const int s = row_start[row];
    const int e = row_start[row + 1];
    if (s == e) return;   // out already holds x@Wr for this row

    float2 acc0 = make_float2(0.f, 0.f);
    float2 acc1 = make_float2(0.f, 0.f);
    int i = s;
    for (; i + 1 < e; i += 2) {
        const int2 e0 = sorted[i];
        const int2 e1 = sorted[i + 1];
        const float2 s0 = *(const float2*)(support + (size_t)e0.x * D + lane * 2);
        const float2 s1 = *(const float2*)(support + (size_t)e1.x * D + lane * 2);
        const float v0 = __int_as_float(e0.y);
        const float v1 = __int_as_float(e1.y);
        acc0.x += s0.x * v0; acc0.y += s0.y * v0;
        acc1.x += s1.x * v1; acc1.y += s1.y * v1;
    }
    if (i < e) {
        const int2 e0 = sorted[i];
        const float2 s0 = *(const float2*)(support + (size_t)e0.x * D + lane * 2);
        const float v0 = __int_as_float(e0.y);
        acc0.x += s0.x * v0; acc0.y += s0.y * v0;
    }
    float* o = out + (size_t)row * D + lane * 2;
    float2 ov = *(const float2*)o;
    ov.x += acc0.x + acc1.x;
    ov.y += acc0.y + acc1.y;
    *(float2*)o = ov;
}

extern "C" void kernel_launch(void* const* d_in, const int* in_sizes, int n_in,
                              void* d_out, int out_size, void* d_ws, size_t ws_size,
                              hipStream_t stream) {
    const float* x     = (const float*)d_in[0];
    const int*   erows = (const int*)d_in[1];
    const int*   ecols = (const int*)d_in[2];
    const float* evals = (const float*)d_in[3];
    const float* W     = (const float*)d_in[4];
    const float* Wr    = (const float*)d_in[5];
    float* out = (float*)d_out;

    const int M = in_sizes[0] / D;   // N = 50000
    const int E = in_sizes[1];       // 800000

    // ws layout
    float* support   = (float*)d_ws;                       // M*D floats
    int*   counts    = (int*)(support + (size_t)M * D);    // M
    int*   row_start = counts + M;                         // M+2
    int*   cursor    = row_start + M + 2;                  // M
    int2*  sorted    = (int2*)(cursor + M);                // E int2
    int*   block_sums= (int*)(sorted + E);                 // ~64

    const int NB = (M + 1023) / 1024;   // 49

    // 1. GEMMs
    dim3 grid((M + 63) / 64, 4);
    gemm_dual<<<grid, 256, 0, stream>>>(x, W, Wr, support, out, M);

    // 2. CSR build
    hipMemsetAsync(counts, 0, (size_t)M * sizeof(int), stream);
    const int eb = (E + 255) / 256;
    edge_histogram<<<eb, 256, 0, stream>>>(erows, counts, E);
    scan_local<<<NB, 256, 0, stream>>>(counts, row_start, block_sums, M);
    scan_blocks<<<1, 64, 0, stream>>>(block_sums, row_start, NB, M);
    add_offsets<<<NB, 256, 0, stream>>>(block_sums, row_start, cursor, M);
    edge_scatter<<<eb, 256, 0, stream>>>(erows, ecols, evals, cursor, sorted, E);

    // 3. Aggregate (wave per row)
    row_aggregate<<<(M + 3) / 4, 256, 0, stream>>>(row_start, sorted, support, out, M);
}

// Round 4
// 247.945 us; speedup vs baseline: 3.1394x; 1.1498x over previous
//
#include <hip/hip_runtime.h>

#define D 128

typedef short short8 __attribute__((ext_vector_type(8)));
typedef float v4f __attribute__((ext_vector_type(4)));

static __device__ __forceinline__ unsigned short f2bf(float f) {
    unsigned u = __builtin_bit_cast(unsigned, f);
    u = (u + 0x7FFFu + ((u >> 16) & 1u)) >> 16;   // RNE
    return (unsigned short)u;
}

// ---------------- prep: Wt[n][k] = (W||Wr)[k][n] as bf16; zero counts -------
__global__ __launch_bounds__(256) void prep(
    const float* __restrict__ W, const float* __restrict__ Wr,
    unsigned short* __restrict__ Wt, int* __restrict__ counts, int M)
{
    const int gid = blockIdx.x * 256 + threadIdx.x;
    if (gid < 2 * D * D) {
        const int k  = gid >> 8;      // 0..127
        const int nn = gid & 255;     // 0..255 (0..127 -> W, 128..255 -> Wr)
        const float v = (nn < D) ? W[k * D + nn] : Wr[k * D + (nn - D)];
        Wt[nn * D + k] = f2bf(v);
    }
    if (gid < M) counts[gid] = 0;
}

// ---------------- MFMA dual GEMM: support(bf16) = x@W, out(f32) = x@Wr ------
// Block: 64 rows x 256 combined cols. Wave w -> cols [64w, 64w+64):
// w=0,1 -> support cols 0..127 ; w=2,3 -> out cols 0..127.
__global__ __launch_bounds__(256) void gemm_dual_mfma(
    const float* __restrict__ x, const unsigned short* __restrict__ Wt,
    unsigned short* __restrict__ support, float* __restrict__ out, int M)
{
    __shared__ unsigned short As[64][136];   // +8 pad -> 2-way bank alias only
    const int tid = threadIdx.x;
    const int w = tid >> 6;
    const int lane = tid & 63;
    const int nl = lane & 15, quad = lane >> 4;
    const int rowBase = blockIdx.x * 64;

    // stage A: fp32 -> bf16 -> LDS. thread t: row t&63, cols (t>>6)*32..+31
    {
        const int r = tid & 63;
        const int seg = tid >> 6;
        const int row = rowBase + r;
        unsigned short tmp[32];
        if (row < M) {
            const float4* src = (const float4*)(x + (size_t)row * D + seg * 32);
            #pragma unroll
            for (int j = 0; j < 8; ++j) {
                const float4 v = src[j];
                tmp[j * 4 + 0] = f2bf(v.x); tmp[j * 4 + 1] = f2bf(v.y);
                tmp[j * 4 + 2] = f2bf(v.z); tmp[j * 4 + 3] = f2bf(v.w);
            }
        } else {
            #pragma unroll
            for (int j = 0; j < 32; ++j) tmp[j] = 0;
        }
        #pragma unroll
        for (int j = 0; j < 4; ++j)
            *(short8*)&As[r][seg * 32 + j * 8] = *(const short8*)&tmp[j * 8];
    }

    // preload B fragments from Wt (L2-hot): lane holds B[n=nl][k=quad*8+j]
    short8 bfrag[4][4];   // [kchunk][ntile]
    {
        const unsigned short* wbase = Wt + (size_t)(w * 64 + nl) * D + quad * 8;
        #pragma unroll
        for (int nt = 0; nt < 4; ++nt)
            #pragma unroll
            for (int c = 0; c < 4; ++c)
                bfrag[c][nt] = *(const short8*)(wbase + (size_t)nt * 16 * D + c * 32);
    }
    __syncthreads();

    v4f acc[4][4] = {};   // [mtile][ntile]
    #pragma unroll
    for (int c = 0; c < 4; ++c) {
        short8 afr[4];
        #pragma unroll
        for (int mt = 0; mt < 4; ++mt)
            afr[mt] = *(const short8*)&As[mt * 16 + nl][c * 32 + quad * 8];
        #pragma unroll
        for (int mt = 0; mt < 4; ++mt)
            #pragma unroll
            for (int nt = 0; nt < 4; ++nt)
                acc[mt][nt] = __builtin_amdgcn_mfma_f32_16x16x32_bf16(
                    afr[mt], bfrag[c][nt], acc[mt][nt], 0, 0, 0);
    }

    // epilogue: D col = nl, row = quad*4 + reg
    const int cbase = (w & 1) * 64;
    if (w < 2) {
        #pragma unroll
        for (int mt = 0; mt < 4; ++mt)
            #pragma unroll
            for (int reg = 0; reg < 4; ++reg) {
                const int row = rowBase + mt * 16 + quad * 4 + reg;
                if (row < M) {
                    #pragma unroll
                    for (int nt = 0; nt < 4; ++nt)
                        support[(size_t)row * D + cbase + nt * 16 + nl] = f2bf(acc[mt][nt][reg]);
                }
            }
    } else {
        #pragma unroll
        for (int mt = 0; mt < 4; ++mt)
            #pragma unroll
            for (int reg = 0; reg < 4; ++reg) {
                const int row = rowBase + mt * 16 + quad * 4 + reg;
                if (row < M) {
                    #pragma unroll
                    for (int nt = 0; nt < 4; ++nt)
                        out[(size_t)row * D + cbase + nt * 16 + nl] = acc[mt][nt][reg];
                }
            }
    }
}

// ---------------- CSR build ------------------------------------------------
__global__ __launch_bounds__(256) void edge_histogram(
    const int* __restrict__ rows, int* __restrict__ counts, int E)
{
    const int e = blockIdx.x * 256 + threadIdx.x;
    if (e < E) atomicAdd(&counts[rows[e]], 1);
}

__global__ __launch_bounds__(256) void scan_local(
    const int* __restrict__ counts, int* __restrict__ row_start,
    int* __restrict__ block_sums, int n)
{
    __shared__ int tmp[256];
    const int b = blockIdx.x, t = threadIdx.x;
    const int base = b * 1024 + t * 4;
    int v0 = 0, v1 = 0, v2 = 0, v3 = 0;
    if (base + 3 < n) {
        const int4 q = *(const int4*)(counts + base);
        v0 = q.x; v1 = q.y; v2 = q.z; v3 = q.w;
    } else {
        if (base + 0 < n) v0 = counts[base + 0];
        if (base + 1 < n) v1 = counts[base + 1];
        if (base + 2 < n) v2 = counts[base + 2];
    }
    const int s01 = v0 + v1;
    const int tsum = s01 + v2 + v3;
    tmp[t] = tsum;
    __syncthreads();
    for (int off = 1; off < 256; off <<= 1) {
        const int u = (t >= off) ? tmp[t - off] : 0;
        __syncthreads();
        tmp[t] += u;
        __syncthreads();
    }
    const int excl = tmp[t] - tsum;
    const int e0 = excl, e1 = excl + v0, e2 = excl + s01, e3 = e2 + v2;
    if (base + 3 < n) {
        *(int4*)(row_start + base) = make_int4(e0, e1, e2, e3);
    } else {
        if (base + 0 < n) row_start[base + 0] = e0;
        if (base + 1 < n) row_start[base + 1] = e1;
        if (base + 2 < n) row_start[base + 2] = e2;
    }
    if (t == 255) block_sums[b] = tmp[255];
}

__global__ __launch_bounds__(64) void scan_blocks(
    int* __restrict__ block_sums, int* __restrict__ row_start, int nb, int n)
{
    __shared__ int tmp[64];
    const int t = threadIdx.x;
    const int v = (t < nb) ? block_sums[t] : 0;
    tmp[t] = v;
    __syncthreads();
    for (int off = 1; off < 64; off <<= 1) {
        const int u = (t >= off) ? tmp[t - off] : 0;
        __syncthreads();
        tmp[t] += u;
        __syncthreads();
    }
    if (t < nb) block_sums[t] = tmp[t] - v;
    if (t == 63) row_start[n] = tmp[63];
}

__global__ __launch_bounds__(256) void add_offsets(
    const int* __restrict__ block_sums, int* __restrict__ row_start,
    int* __restrict__ cursor, int n)
{
    const int b = blockIdx.x;
    const int off = block_sums[b];
    const int base = b * 1024 + threadIdx.x * 4;
    if (base + 3 < n) {
        int4 q = *(const int4*)(row_start + base);
        q.x += off; q.y += off; q.z += off; q.w += off;
        *(int4*)(row_start + base) = q;
        *(int4*)(cursor + base) = q;
    } else {
        #pragma unroll
        for (int j = 0; j < 4; ++j) {
            const int i = base + j;
            if (i < n) {
                const int v = row_start[i] + off;
                row_start[i] = v;
                cursor[i] = v;
            }
        }
    }
}

__global__ __launch_bounds__(256) void edge_scatter(
    const int* __restrict__ rows, const int* __restrict__ cols,
    const float* __restrict__ vals, int* __restrict__ cursor,
    int2* __restrict__ sorted, int E)
{
    const int e = blockIdx.x * 256 + threadIdx.x;
    if (e >= E) return;
    const int r = rows[e];
    const int pos = atomicAdd(&cursor[r], 1);
    sorted[pos] = make_int2(cols[e], __float_as_int(vals[e]));
}

// ---------------- Aggregation: wave per row, bf16 gather -------------------
__global__ __launch_bounds__(256) void row_aggregate(
    const int* __restrict__ row_start, const int2* __restrict__ sorted,
    const unsigned short* __restrict__ support, float* __restrict__ out, int N)
{
    const int row = blockIdx.x * 4 + (threadIdx.x >> 6);
    const int lane = threadIdx.x & 63;
    if (row >= N) return;
    const int s = row_start[row];
    const int e = row_start[row + 1];
    if (s == e) return;

    float ax = 0.f, ay = 0.f, bx = 0.f, by = 0.f;
    int i = s;
    for (; i + 1 < e; i += 2) {
        const int2 e0 = sorted[i];
        const int2 e1 = sorted[i + 1];
        const unsigned p0 = *(const unsigned*)(support + (size_t)e0.x * D + lane * 2);
        const unsigned p1 = *(const unsigned*)(support + (size_t)e1.x * D + lane * 2);
        const float v0 = __int_as_float(e0.y);
        const float v1 = __int_as_float(e1.y);
        ax += __builtin_bit_cast(float, p0 << 16) * v0;
        ay += __builtin_bit_cast(float, p0 & 0xFFFF0000u) * v0;
        bx += __builtin_bit_cast(float, p1 << 16) * v1;
        by += __builtin_bit_cast(float, p1 & 0xFFFF0000u) * v1;
    }
    if (i < e) {
        const int2 e0 = sorted[i];
        const unsigned p0 = *(const unsigned*)(support + (size_t)e0.x * D + lane * 2);
        const float v0 = __int_as_float(e0.y);
        ax += __builtin_bit_cast(float, p0 << 16) * v0;
        ay += __builtin_bit_cast(float, p0 & 0xFFFF0000u) * v0;
    }
    float* o = out + (size_t)row * D + lane * 2;
    float2 ov = *(const float2*)o;
    ov.x += ax + bx;
    ov.y += ay + by;
    *(float2*)o = ov;
}

extern "C" void kernel_launch(void* const* d_in, const int* in_sizes, int n_in,
                              void* d_out, int out_size, void* d_ws, size_t ws_size,
                              hipStream_t stream) {
    const float* x     = (const float*)d_in[0];
    const int*   erows = (const int*)d_in[1];
    const int*   ecols = (const int*)d_in[2];
    const float* evals = (const float*)d_in[3];
    const float* W     = (const float*)d_in[4];
    const float* Wr    = (const float*)d_in[5];
    float* out = (float*)d_out;

    const int M = in_sizes[0] / D;   // 50000
    const int E = in_sizes[1];       // 800000

    // ws layout (all offsets 8B-aligned)
    unsigned short* support = (unsigned short*)d_ws;            // M*D bf16
    unsigned short* Wt      = support + (size_t)M * D;          // 2*D*D bf16
    int*   counts     = (int*)(Wt + 2 * D * D);                 // M
    int*   row_start  = counts + M;                             // M+2
    int*   cursor     = row_start + M + 2;                      // M
    int*   block_sums = cursor + M;                             // 64
    int2*  sorted     = (int2*)(block_sums + 64);               // E

    const int NB = (M + 1023) / 1024;           // 49
    const int eb = (E + 255) / 256;
    const int prep_grid = ((M > 2 * D * D ? M : 2 * D * D) + 255) / 256;

    prep<<<prep_grid, 256, 0, stream>>>(W, Wr, Wt, counts, M);
    gemm_dual_mfma<<<(M + 63) / 64, 256, 0, stream>>>(x, Wt, support, out, M);
    edge_histogram<<<eb, 256, 0, stream>>>(erows, counts, E);
    scan_local<<<NB, 256, 0, stream>>>(counts, row_start, block_sums, M);
    scan_blocks<<<1, 64, 0, stream>>>(block_sums, row_start, NB, M);
    add_offsets<<<NB, 256, 0, stream>>>(block_sums, row_start, cursor, M);
    edge_scatter<<<eb, 256, 0, stream>>>(erows, ecols, evals, cursor, sorted, E);
    row_aggregate<<<(M + 3) / 4, 256, 0, stream>>>(row_start, sorted, support, out, M);
}

// Round 5
// 230.513 us; speedup vs baseline: 3.3768x; 1.0756x over previous
//
#include <hip/hip_runtime.h>

#define D 128

typedef short short8 __attribute__((ext_vector_type(8)));
typedef float v4f __attribute__((ext_vector_type(4)));

static __device__ __forceinline__ unsigned short f2bf(float f) {
    unsigned u = __builtin_bit_cast(unsigned, f);
    u = (u + 0x7FFFu + ((u >> 16) & 1u)) >> 16;   // RNE
    return (unsigned short)u;
}

// ---------------- prep: Wt[n][k] = (W||Wr)[k][n] as bf16; zero counts -------
__global__ __launch_bounds__(256) void prep(
    const float* __restrict__ W, const float* __restrict__ Wr,
    unsigned short* __restrict__ Wt, int* __restrict__ counts, int M)
{
    const int gid = blockIdx.x * 256 + threadIdx.x;
    if (gid < 2 * D * D) {
        const int k  = gid >> 8;      // 0..127
        const int nn = gid & 255;     // 0..255 (0..127 -> W, 128..255 -> Wr)
        const float v = (nn < D) ? W[k * D + nn] : Wr[k * D + (nn - D)];
        Wt[nn * D + k] = f2bf(v);
    }
    if (gid < M) counts[gid] = 0;
}

// ---------------- MFMA dual GEMM: support(bf16) = x@W, out(f32) = x@Wr ------
__global__ __launch_bounds__(256) void gemm_dual_mfma(
    const float* __restrict__ x, const unsigned short* __restrict__ Wt,
    unsigned short* __restrict__ support, float* __restrict__ out, int M)
{
    __shared__ unsigned short As[64][136];
    const int tid = threadIdx.x;
    const int w = tid >> 6;
    const int lane = tid & 63;
    const int nl = lane & 15, quad = lane >> 4;
    const int rowBase = blockIdx.x * 64;

    {
        const int r = tid & 63;
        const int seg = tid >> 6;
        const int row = rowBase + r;
        unsigned short tmp[32];
        if (row < M) {
            const float4* src = (const float4*)(x + (size_t)row * D + seg * 32);
            #pragma unroll
            for (int j = 0; j < 8; ++j) {
                const float4 v = src[j];
                tmp[j * 4 + 0] = f2bf(v.x); tmp[j * 4 + 1] = f2bf(v.y);
                tmp[j * 4 + 2] = f2bf(v.z); tmp[j * 4 + 3] = f2bf(v.w);
            }
        } else {
            #pragma unroll
            for (int j = 0; j < 32; ++j) tmp[j] = 0;
        }
        #pragma unroll
        for (int j = 0; j < 4; ++j)
            *(short8*)&As[r][seg * 32 + j * 8] = *(const short8*)&tmp[j * 8];
    }

    short8 bfrag[4][4];
    {
        const unsigned short* wbase = Wt + (size_t)(w * 64 + nl) * D + quad * 8;
        #pragma unroll
        for (int nt = 0; nt < 4; ++nt)
            #pragma unroll
            for (int c = 0; c < 4; ++c)
                bfrag[c][nt] = *(const short8*)(wbase + (size_t)nt * 16 * D + c * 32);
    }
    __syncthreads();

    v4f acc[4][4] = {};
    #pragma unroll
    for (int c = 0; c < 4; ++c) {
        short8 afr[4];
        #pragma unroll
        for (int mt = 0; mt < 4; ++mt)
            afr[mt] = *(const short8*)&As[mt * 16 + nl][c * 32 + quad * 8];
        #pragma unroll
        for (int mt = 0; mt < 4; ++mt)
            #pragma unroll
            for (int nt = 0; nt < 4; ++nt)
                acc[mt][nt] = __builtin_amdgcn_mfma_f32_16x16x32_bf16(
                    afr[mt], bfrag[c][nt], acc[mt][nt], 0, 0, 0);
    }

    const int cbase = (w & 1) * 64;
    if (w < 2) {
        #pragma unroll
        for (int mt = 0; mt < 4; ++mt)
            #pragma unroll
            for (int reg = 0; reg < 4; ++reg) {
                const int row = rowBase + mt * 16 + quad * 4 + reg;
                if (row < M) {
                    #pragma unroll
                    for (int nt = 0; nt < 4; ++nt)
                        support[(size_t)row * D + cbase + nt * 16 + nl] = f2bf(acc[mt][nt][reg]);
                }
            }
    } else {
        #pragma unroll
        for (int mt = 0; mt < 4; ++mt)
            #pragma unroll
            for (int reg = 0; reg < 4; ++reg) {
                const int row = rowBase + mt * 16 + quad * 4 + reg;
                if (row < M) {
                    #pragma unroll
                    for (int nt = 0; nt < 4; ++nt)
                        out[(size_t)row * D + cbase + nt * 16 + nl] = acc[mt][nt][reg];
                }
            }
    }
}

// ---------------- CSR build ------------------------------------------------
__global__ __launch_bounds__(256) void edge_histogram(
    const int* __restrict__ rows, int* __restrict__ counts, int E)
{
    const int e = blockIdx.x * 256 + threadIdx.x;
    if (e < E) atomicAdd(&counts[rows[e]], 1);
}

__global__ __launch_bounds__(256) void scan_local(
    const int* __restrict__ counts, int* __restrict__ row_start,
    int* __restrict__ block_sums, int n)
{
    __shared__ int tmp[256];
    const int b = blockIdx.x, t = threadIdx.x;
    const int base = b * 1024 + t * 4;
    int v0 = 0, v1 = 0, v2 = 0, v3 = 0;
    if (base + 3 < n) {
        const int4 q = *(const int4*)(counts + base);
        v0 = q.x; v1 = q.y; v2 = q.z; v3 = q.w;
    } else {
        if (base + 0 < n) v0 = counts[base + 0];
        if (base + 1 < n) v1 = counts[base + 1];
        if (base + 2 < n) v2 = counts[base + 2];
    }
    const int s01 = v0 + v1;
    const int tsum = s01 + v2 + v3;
    tmp[t] = tsum;
    __syncthreads();
    for (int off = 1; off < 256; off <<= 1) {
        const int u = (t >= off) ? tmp[t - off] : 0;
        __syncthreads();
        tmp[t] += u;
        __syncthreads();
    }
    const int excl = tmp[t] - tsum;
    const int e0 = excl, e1 = excl + v0, e2 = excl + s01, e3 = e2 + v2;
    if (base + 3 < n) {
        *(int4*)(row_start + base) = make_int4(e0, e1, e2, e3);
    } else {
        if (base + 0 < n) row_start[base + 0] = e0;
        if (base + 1 < n) row_start[base + 1] = e1;
        if (base + 2 < n) row_start[base + 2] = e2;
    }
    if (t == 255) block_sums[b] = tmp[255];
}

__global__ __launch_bounds__(64) void scan_blocks(
    int* __restrict__ block_sums, int* __restrict__ row_start, int nb, int n)
{
    __shared__ int tmp[64];
    const int t = threadIdx.x;
    const int v = (t < nb) ? block_sums[t] : 0;
    tmp[t] = v;
    __syncthreads();
    for (int off = 1; off < 64; off <<= 1) {
        const int u = (t >= off) ? tmp[t - off] : 0;
        __syncthreads();
        tmp[t] += u;
        __syncthreads();
    }
    if (t < nb) block_sums[t] = tmp[t] - v;
    if (t == 63) row_start[n] = tmp[63];
}

__global__ __launch_bounds__(256) void add_offsets(
    const int* __restrict__ block_sums, int* __restrict__ row_start,
    int* __restrict__ cursor, int n)
{
    const int b = blockIdx.x;
    const int off = block_sums[b];
    const int base = b * 1024 + threadIdx.x * 4;
    if (base + 3 < n) {
        int4 q = *(const int4*)(row_start + base);
        q.x += off; q.y += off; q.z += off; q.w += off;
        *(int4*)(row_start + base) = q;
        *(int4*)(cursor + base) = q;
    } else {
        #pragma unroll
        for (int j = 0; j < 4; ++j) {
            const int i = base + j;
            if (i < n) {
                const int v = row_start[i] + off;
                row_start[i] = v;
                cursor[i] = v;
            }
        }
    }
}

__global__ __launch_bounds__(256) void edge_scatter(
    const int* __restrict__ rows, const int* __restrict__ cols,
    const float* __restrict__ vals, int* __restrict__ cursor,
    int2* __restrict__ sorted, int E)
{
    const int e = blockIdx.x * 256 + threadIdx.x;
    if (e >= E) return;
    const int r = rows[e];
    const int pos = atomicAdd(&cursor[r], 1);
    sorted[pos] = make_int2(cols[e], __float_as_int(vals[e]));
}

// ---------------- Aggregation: wave per row, batched independent gathers ----
__global__ __launch_bounds__(256) void row_aggregate(
    const int* __restrict__ row_start, const int2* __restrict__ sorted,
    const unsigned short* __restrict__ support, float* __restrict__ out, int N)
{
    const int row = blockIdx.x * 4 + (threadIdx.x >> 6);
    const int lane = threadIdx.x & 63;
    if (row >= N) return;
    const int s = row_start[row];
    const int e = row_start[row + 1];
    if (s == e) return;

    float ax = 0.f, ay = 0.f;
    int i = s;

    // full batches of 8: load 8 descriptors (4x int4 uniform), then 8
    // independent gathers, then math.
    for (; i + 8 <= e; i += 8) {
        int4 q0 = *(const int4*)(sorted + i + 0);
        int4 q1 = *(const int4*)(sorted + i + 2);
        int4 q2 = *(const int4*)(sorted + i + 4);
        int4 q3 = *(const int4*)(sorted + i + 6);
        const int  c[8] = {q0.x, q0.z, q1.x, q1.z, q2.x, q2.z, q3.x, q3.z};
        const int  vv[8] = {q0.y, q0.w, q1.y, q1.w, q2.y, q2.w, q3.y, q3.w};
        unsigned p[8];
        #pragma unroll
        for (int j = 0; j < 8; ++j)
            p[j] = *(const unsigned*)(support + (size_t)c[j] * D + lane * 2);
        #pragma unroll
        for (int j = 0; j < 8; ++j) {
            const float v = __int_as_float(vv[j]);
            ax += __builtin_bit_cast(float, p[j] << 16) * v;
            ay += __builtin_bit_cast(float, p[j] & 0xFFFF0000u) * v;
        }
    }

    // masked tail batch (clamped duplicate gathers hit the same line: cheap)
    if (i < e) {
        const int m = e - i;   // 1..7
        int cc[8]; float vv[8];
        #pragma unroll
        for (int j = 0; j < 8; ++j) {
            const int idx = i + (j < m ? j : m - 1);
            const int2 ed = sorted[idx];
            cc[j] = ed.x;
            vv[j] = (j < m) ? __int_as_float(ed.y) : 0.f;
        }
        unsigned p[8];
        #pragma unroll
        for (int j = 0; j < 8; ++j)
            p[j] = *(const unsigned*)(support + (size_t)cc[j] * D + lane * 2);
        #pragma unroll
        for (int j = 0; j < 8; ++j) {
            ax += __builtin_bit_cast(float, p[j] << 16) * vv[j];
            ay += __builtin_bit_cast(float, p[j] & 0xFFFF0000u) * vv[j];
        }
    }

    float* o = out + (size_t)row * D + lane * 2;
    float2 ov = *(const float2*)o;
    ov.x += ax;
    ov.y += ay;
    *(float2*)o = ov;
}

extern "C" void kernel_launch(void* const* d_in, const int* in_sizes, int n_in,
                              void* d_out, int out_size, void* d_ws, size_t ws_size,
                              hipStream_t stream) {
    const float* x     = (const float*)d_in[0];
    const int*   erows = (const int*)d_in[1];
    const int*   ecols = (const int*)d_in[2];
    const float* evals = (const float*)d_in[3];
    const float* W     = (const float*)d_in[4];
    const float* Wr    = (const float*)d_in[5];
    float* out = (float*)d_out;

    const int M = in_sizes[0] / D;   // 50000
    const int E = in_sizes[1];       // 800000

    unsigned short* support = (unsigned short*)d_ws;            // M*D bf16
    unsigned short* Wt      = support + (size_t)M * D;          // 2*D*D bf16
    int*   counts     = (int*)(Wt + 2 * D * D);                 // M
    int*   row_start  = counts + M;                             // M+2
    int*   cursor     = row_start + M + 2;                      // M
    int*   block_sums = cursor + M;                             // 64
    int2*  sorted     = (int2*)(block_sums + 64);               // E

    const int NB = (M + 1023) / 1024;           // 49
    const int eb = (E + 255) / 256;
    const int prep_grid = ((M > 2 * D * D ? M : 2 * D * D) + 255) / 256;

    prep<<<prep_grid, 256, 0, stream>>>(W, Wr, Wt, counts, M);
    gemm_dual_mfma<<<(M + 63) / 64, 256, 0, stream>>>(x, Wt, support, out, M);
    edge_histogram<<<eb, 256, 0, stream>>>(erows, counts, E);
    scan_local<<<NB, 256, 0, stream>>>(counts, row_start, block_sums, M);
    scan_blocks<<<1, 64, 0, stream>>>(block_sums, row_start, NB, M);
    add_offsets<<<NB, 256, 0, stream>>>(block_sums, row_start, cursor, M);
    edge_scatter<<<eb, 256, 0, stream>>>(erows, ecols, evals, cursor, sorted, E);
    row_aggregate<<<(M + 3) / 4, 256, 0, stream>>>(row_start, sorted, support, out, M);
}